// Round 7
// baseline (225.567 us; speedup 1.0000x reference)
//
#include <hip/hip_runtime.h>

// IF neuron, multi-step, hard reset:
//   h_t = x_t + v_{t-1};  s_t = (h_t >= 1.0);  v_t = s_t ? 0 : h_t
//
// R13: final untested axis = TLP in the NT regime. R9's negative TLP
// result was plain-load (L3-hit-shortened latency, contention-dominated
// -> invalid test, same logic that invalidated R8's store test). With NT
// loads every read is a ~900cy HBM miss; queue-fill needs issue-eligible
// waves. R12 ran only 8 waves/CU (512 blocks). This round: C=2 -> C=1
// at f4 (single variable): 1024 blocks = 4 blocks/CU = 16 waves/CU.
//
// Pre-committed: neutral/negative -> all axes swept, revert to best and
// declare roofline next round.

typedef float v4f __attribute__((ext_vector_type(4)));
typedef float v2f __attribute__((ext_vector_type(2)));

template <int T>
__global__ __launch_bounds__(256) void if_node_f4nt_tlp(
    const float* __restrict__ x,    // (T, N)
    const float* __restrict__ v0,   // (N,)
    float* __restrict__ out,        // (T, N)
    long n4)                        // N/4
{
    long i = (long)blockIdx.x * blockDim.x + threadIdx.x;
    if (i >= n4) return;

    const v4f* __restrict__ x4 = (const v4f*)x;
    v4f*       __restrict__ o4 = (v4f*)out;

    v4f v = ((const v4f*)v0)[i];

#pragma unroll
    for (int t = 0; t < T; ++t) {
        v4f xv = __builtin_nontemporal_load(&x4[(long)t * n4 + i]);
        v4f s;
#pragma unroll
        for (int e = 0; e < 4; ++e) {
            float h = xv[e] + v[e];
            bool sp = h >= 1.0f;    // == (h - 1.0f) >= 0 for all finite h
            s[e] = sp ? 1.0f : 0.0f;
            v[e] = sp ? 0.0f : h;
        }
        __builtin_nontemporal_store(s, &o4[(long)t * n4 + i]);
    }
}

// Fallbacks for shapes the fast path doesn't cover.
__global__ __launch_bounds__(256) void if_node_f2_generic(
    const float* __restrict__ x, const float* __restrict__ v0,
    float* __restrict__ out, long n2, int T)
{
    long i = (long)blockIdx.x * blockDim.x + threadIdx.x;
    if (i >= n2) return;
    const v2f* x2 = (const v2f*)x;
    v2f*       o2 = (v2f*)out;
    v2f v = ((const v2f*)v0)[i];
    for (int t = 0; t < T; ++t) {
        v2f xv = x2[(long)t * n2 + i];
        float hx = xv.x + v.x;
        float hy = xv.y + v.y;
        bool sx = hx >= 1.0f;
        bool sy = hy >= 1.0f;
        v2f s;
        s.x = sx ? 1.0f : 0.0f;
        s.y = sy ? 1.0f : 0.0f;
        v.x = sx ? 0.0f : hx;
        v.y = sy ? 0.0f : hy;
        o2[(long)t * n2 + i] = s;
    }
}

__global__ __launch_bounds__(256) void if_node_scalar(
    const float* __restrict__ x, const float* __restrict__ v0,
    float* __restrict__ out, long n, int T)
{
    long i = (long)blockIdx.x * blockDim.x + threadIdx.x;
    if (i >= n) return;
    float v = v0[i];
    for (int t = 0; t < T; ++t) {
        float h = x[(long)t * n + i] + v;
        bool s = h >= 1.0f;
        out[(long)t * n + i] = s ? 1.0f : 0.0f;
        v = s ? 0.0f : h;
    }
}

extern "C" void kernel_launch(void* const* d_in, const int* in_sizes, int n_in,
                              void* d_out, int out_size, void* d_ws, size_t ws_size,
                              hipStream_t stream) {
    const float* x  = (const float*)d_in[0];   // (T, B, D) fp32
    const float* v0 = (const float*)d_in[1];   // (B, D) fp32
    float* out = (float*)d_out;                // (T, B, D) fp32

    long n = in_sizes[1];                      // B*D
    int  T = (int)(in_sizes[0] / n);           // 32

    int block = 256;
    if (T == 32 && (n % 4) == 0) {
        long n4 = n >> 2;                      // float4 elements
        long grid = (n4 + block - 1) / block;  // 1024 blocks at N=1M
        if_node_f4nt_tlp<32><<<dim3((unsigned)grid), dim3(block), 0, stream>>>(
            x, v0, out, n4);
    } else if ((n & 1) == 0) {
        long n2 = n >> 1;
        long grid = (n2 + block - 1) / block;
        if_node_f2_generic<<<dim3((unsigned)grid), dim3(block), 0, stream>>>(
            x, v0, out, n2, T);
    } else {
        long grid = (n + block - 1) / block;
        if_node_scalar<<<dim3((unsigned)grid), dim3(block), 0, stream>>>(
            x, v0, out, n, T);
    }
}

// Round 8
// 222.670 us; speedup vs baseline: 1.0130x; 1.0130x over previous
//
#include <hip/hip_runtime.h>

// IF neuron, multi-step, hard reset:
//   h_t = x_t + v_{t-1};  s_t = (h_t >= 1.0);  v_t = s_t ? 0 : h_t
//
// FINAL (R14 = revert to R12, best measured: 219.5 us bench).
// Session findings:
//  - NT LOADS are the one real lever (+10 us): x-reads allocating in L3
//    caused read/write contention (out write-allocate + x read-allocate
//    = exactly 256 MiB = L3 size, mutual eviction).
//  - Store cache policy: neutral (R8 dirty-regime, R11 clean-regime).
//  - Prefetch depth 0-4, phase split, bit-pack: neutral to negative --
//    the CU issue side was never the limit (VALUBusy ~5%).
//  - TLP 8->16->32 waves/CU: neutral to negative in both regimes.
//  - f4 vs f2: ~2 us (request-rate, marginal).
// Ceiling: ~4.1 TB/s for the concurrent uncached read+write mix; no
// measured witness on this part serves that mix at the 6.3 TB/s
// single-stream rate. All CU-side axes swept.

typedef float v4f __attribute__((ext_vector_type(4)));
typedef float v2f __attribute__((ext_vector_type(2)));

template <int T, int C>
__global__ __launch_bounds__(256) void if_node_mc_f4nt(
    const float* __restrict__ x,    // (T, N)
    const float* __restrict__ v0,   // (N,)
    float* __restrict__ out,        // (T, N)
    long q)                         // column stride in float4 elems = (N/4)/C
{
    long i = (long)blockIdx.x * blockDim.x + threadIdx.x;
    if (i >= q) return;

    const v4f* __restrict__ x4 = (const v4f*)x;
    v4f*       __restrict__ o4 = (v4f*)out;
    const v4f* __restrict__ vv = (const v4f*)v0;

    const long n4 = q * C;

    v4f v[C];
#pragma unroll
    for (int c = 0; c < C; ++c)
        v[c] = vv[i + (long)c * q];

#pragma unroll
    for (int t = 0; t < T; ++t) {
        v4f xv[C];
#pragma unroll
        for (int c = 0; c < C; ++c)
            xv[c] = __builtin_nontemporal_load(&x4[(long)t * n4 + i + (long)c * q]);

#pragma unroll
        for (int c = 0; c < C; ++c) {
            v4f s;
#pragma unroll
            for (int e = 0; e < 4; ++e) {
                float h = xv[c][e] + v[c][e];
                bool sp = h >= 1.0f;   // == (h - 1.0f) >= 0 for all finite h
                s[e] = sp ? 1.0f : 0.0f;
                v[c][e] = sp ? 0.0f : h;
            }
            __builtin_nontemporal_store(s, &o4[(long)t * n4 + i + (long)c * q]);
        }
    }
}

// Fallbacks for shapes the fast path doesn't cover.
__global__ __launch_bounds__(256) void if_node_f2_generic(
    const float* __restrict__ x, const float* __restrict__ v0,
    float* __restrict__ out, long n2, int T)
{
    long i = (long)blockIdx.x * blockDim.x + threadIdx.x;
    if (i >= n2) return;
    const v2f* x2 = (const v2f*)x;
    v2f*       o2 = (v2f*)out;
    v2f v = ((const v2f*)v0)[i];
    for (int t = 0; t < T; ++t) {
        v2f xv = x2[(long)t * n2 + i];
        float hx = xv.x + v.x;
        float hy = xv.y + v.y;
        bool sx = hx >= 1.0f;
        bool sy = hy >= 1.0f;
        v2f s;
        s.x = sx ? 1.0f : 0.0f;
        s.y = sy ? 1.0f : 0.0f;
        v.x = sx ? 0.0f : hx;
        v.y = sy ? 0.0f : hy;
        o2[(long)t * n2 + i] = s;
    }
}

__global__ __launch_bounds__(256) void if_node_scalar(
    const float* __restrict__ x, const float* __restrict__ v0,
    float* __restrict__ out, long n, int T)
{
    long i = (long)blockIdx.x * blockDim.x + threadIdx.x;
    if (i >= n) return;
    float v = v0[i];
    for (int t = 0; t < T; ++t) {
        float h = x[(long)t * n + i] + v;
        bool s = h >= 1.0f;
        out[(long)t * n + i] = s ? 1.0f : 0.0f;
        v = s ? 0.0f : h;
    }
}

extern "C" void kernel_launch(void* const* d_in, const int* in_sizes, int n_in,
                              void* d_out, int out_size, void* d_ws, size_t ws_size,
                              hipStream_t stream) {
    const float* x  = (const float*)d_in[0];   // (T, B, D) fp32
    const float* v0 = (const float*)d_in[1];   // (B, D) fp32
    float* out = (float*)d_out;                // (T, B, D) fp32

    long n = in_sizes[1];                      // B*D
    int  T = (int)(in_sizes[0] / n);           // 32

    int block = 256;
    constexpr int C = 2;
    if (T == 32 && (n % (4 * C)) == 0) {
        long n4 = n >> 2;          // float4 elements
        long q  = n4 / C;          // per-column float4 elements
        long grid = (q + block - 1) / block;
        if_node_mc_f4nt<32, C><<<dim3((unsigned)grid), dim3(block), 0, stream>>>(
            x, v0, out, q);
    } else if ((n & 1) == 0) {
        long n2 = n >> 1;
        long grid = (n2 + block - 1) / block;
        if_node_f2_generic<<<dim3((unsigned)grid), dim3(block), 0, stream>>>(
            x, v0, out, n2, T);
    } else {
        long grid = (n + block - 1) / block;
        if_node_scalar<<<dim3((unsigned)grid), dim3(block), 0, stream>>>(
            x, v0, out, n, T);
    }
}